// Round 3
// baseline (253.668 us; speedup 1.0000x reference)
//
#include <hip/hip_runtime.h>
#include <math.h>
#include <stdint.h>

#define N512 512

typedef __attribute__((ext_vector_type(8))) short short8;
typedef __attribute__((ext_vector_type(4))) float floatx4;

__device__ __forceinline__ short f2bf(float f) {
    uint32_t u = __float_as_uint(f);
    uint32_t r = u + 0x7fffu + ((u >> 16) & 1u);
    return (short)(r >> 16);
}

// cheap round-half-up (2 VALU): fine vs 0.109 threshold
__device__ __forceinline__ short f2bf_fast(float f) {
    return (short)((__float_as_uint(f) + 0x8000u) >> 16);
}

__device__ __forceinline__ void gload_lds16(const void* g, void* l) {
    __builtin_amdgcn_global_load_lds(
        (const __attribute__((address_space(1))) void*)g,
        (__attribute__((address_space(3))) void*)l,
        16, 0, 0);
}

// M[n,k] = s_k * cos(pi * k * (2n+1) / (2N)), bf16 (RNE-ish)
__global__ __launch_bounds__(256) void build_idct_matrix_bf16(short* __restrict__ M) {
    int idx = blockIdx.x * 256 + threadIdx.x;
    int n = idx >> 9;
    int k = idx & 511;
    int j = (k * (2 * n + 1)) & (4 * N512 - 1);
    float theta = (float)j * (3.14159265358979323846f / (2.0f * (float)N512));
    float s = (k == 0) ? 0.044194173824159216f : 0.0625f;
    M[idx] = f2bf(s * cosf(theta));
}

// ---------------------------------------------------------------------------
// Stage 1 (fused cvt): Tt[z][n][h] = sum_k M[n,k] * X[z][h,k]
// A = M bf16 via global_load_lds(16B, XOR-swizzled); B = X fp32, loaded as
// float4, converted in-register to bf16, ds_write_b128 into the SAME swizzled
// layout. 128x128 tile, BK=64, 4 waves, 4x4 of 16x16x32 bf16 MFMA each.
// ---------------------------------------------------------------------------
__global__ __launch_bounds__(256) void gemm_s1(const short* __restrict__ A,
                                               const float* __restrict__ Xg,
                                               short* __restrict__ Tg) {
    __shared__ short lds[2 * 8192];   // A tile 128x64 (16KB) | B tile (16KB)
    short* ldsA = lds;
    short* ldsB = lds + 8192;

    const int t = threadIdx.x;
    const int w = t >> 6;          // wave 0..3
    const int l = t & 63;
    const int q = (t >> 4) & 3;    // quad in wave
    const int r = t & 15;

    const int bm0 = blockIdx.y * 128;   // A rows (n)
    const int bn0 = blockIdx.x * 128;   // B rows (h)
    const int wm0 = (w >> 1) * 64;
    const int wn0 = (w & 1) * 64;

    const float* Xs = Xg + ((long)blockIdx.z << 18);
    short* Tt = Tg + ((long)blockIdx.z << 18);

    // A staging: instr i of wave w covers tile rows (w*4+i)*8 .. +7
    const int rsub = l >> 3;                 // row within 8-row chunk
    const int glog = (l & 7) ^ rsub;         // swizzled 16B-group to fetch

    // B staging (fp32->bf16): thread t handles row rt = t>>1, half = t&1
    const int brt = t >> 1;                  // tile row 0..127
    const int bhalf = t & 1;                 // k-offset 32*half
    const int bchunk = brt >> 3;
    const int brsub = brt & 7;
    // LDS short-addresses of the two 16B groups this thread produces
    short* bdst0 = ldsB + bchunk * 512 + brsub * 64 + (((bhalf * 4 + 0) ^ brsub) * 8);
    short* bdst1 = ldsB + bchunk * 512 + brsub * 64 + (((bhalf * 4 + 1) ^ brsub) * 8);
    short* bdst2 = ldsB + bchunk * 512 + brsub * 64 + (((bhalf * 4 + 2) ^ brsub) * 8);
    short* bdst3 = ldsB + bchunk * 512 + brsub * 64 + (((bhalf * 4 + 3) ^ brsub) * 8);

    floatx4 acc[4][4] = {};

    for (int kt = 0; kt < 8; ++kt) {
        const int k0 = kt * 64;
        // A -> LDS via DMA
#pragma unroll
        for (int i = 0; i < 4; ++i) {
            const int chunk = w * 4 + i;
            const int rt = chunk * 8 + rsub;
            gload_lds16(A + (((long)(bm0 + rt)) << 9) + k0 + glog * 8,
                        ldsA + chunk * 512);
        }
        // B: 32 fp32 -> 32 bf16 -> 2x ds_write_b128 (4 groups of 8)
        {
            const float* src = Xs + (((long)(bn0 + brt)) << 9) + k0 + bhalf * 32;
            float4 v[8];
#pragma unroll
            for (int i = 0; i < 8; ++i) v[i] = ((const float4*)src)[i];
            short g[32];
#pragma unroll
            for (int i = 0; i < 8; ++i) {
                g[4 * i + 0] = f2bf_fast(v[i].x);
                g[4 * i + 1] = f2bf_fast(v[i].y);
                g[4 * i + 2] = f2bf_fast(v[i].z);
                g[4 * i + 3] = f2bf_fast(v[i].w);
            }
            *(short8*)bdst0 = *(short8*)&g[0];
            *(short8*)bdst1 = *(short8*)&g[8];
            *(short8*)bdst2 = *(short8*)&g[16];
            *(short8*)bdst3 = *(short8*)&g[24];
        }
        __syncthreads();
#pragma unroll
        for (int kk = 0; kk < 2; ++kk) {
            const int c = kk * 4 + q;
            const int goff = ((c ^ (r & 7)) * 8);
            short8 af[4], bf[4];
#pragma unroll
            for (int i = 0; i < 4; ++i) {
                af[i] = *(const short8*)(ldsA + (wm0 + i * 16 + r) * 64 + goff);
                bf[i] = *(const short8*)(ldsB + (wn0 + i * 16 + r) * 64 + goff);
            }
#pragma unroll
            for (int i = 0; i < 4; ++i)
#pragma unroll
                for (int j = 0; j < 4; ++j)
                    acc[i][j] = __builtin_amdgcn_mfma_f32_16x16x32_bf16(
                        af[i], bf[j], acc[i][j], 0, 0, 0);
        }
        __syncthreads();
    }

    // epilogue: D row = quad*4+reg, col = lane&15 (bf16 out)
#pragma unroll
    for (int i = 0; i < 4; ++i) {
        const int mrow = bm0 + wm0 + i * 16 + q * 4;
#pragma unroll
        for (int j = 0; j < 4; ++j) {
            const int ncol = bn0 + wn0 + j * 16 + r;
#pragma unroll
            for (int rg = 0; rg < 4; ++rg)
                Tt[(long)(mrow + rg) * N512 + ncol] = f2bf(acc[i][j][rg]);
        }
    }
}

// ---------------------------------------------------------------------------
// Stage 2: Out[z][m][n] = sum_h M[m,h] * Tt[z][n,h]  (both bf16, fp32 out)
// ---------------------------------------------------------------------------
__global__ __launch_bounds__(256) void gemm_s2(const short* __restrict__ A,
                                               const short* __restrict__ Bg,
                                               float* __restrict__ Cg) {
    __shared__ short lds[2 * 8192];
    short* ldsA = lds;
    short* ldsB = lds + 8192;

    const int t = threadIdx.x;
    const int w = t >> 6;
    const int l = t & 63;
    const int q = (t >> 4) & 3;
    const int r = t & 15;

    const int bm0 = blockIdx.y * 128;
    const int bn0 = blockIdx.x * 128;
    const int wm0 = (w >> 1) * 64;
    const int wn0 = (w & 1) * 64;

    const short* Bs = Bg + ((long)blockIdx.z << 18);
    float* C = Cg + ((long)blockIdx.z << 18);

    const int rsub = l >> 3;
    const int glog = (l & 7) ^ rsub;

    floatx4 acc[4][4] = {};

    for (int kt = 0; kt < 8; ++kt) {
        const int k0 = kt * 64;
#pragma unroll
        for (int i = 0; i < 4; ++i) {
            const int chunk = w * 4 + i;
            const int rt = chunk * 8 + rsub;
            gload_lds16(A + (((long)(bm0 + rt)) << 9) + k0 + glog * 8,
                        ldsA + chunk * 512);
            gload_lds16(Bs + (((long)(bn0 + rt)) << 9) + k0 + glog * 8,
                        ldsB + chunk * 512);
        }
        __syncthreads();
#pragma unroll
        for (int kk = 0; kk < 2; ++kk) {
            const int c = kk * 4 + q;
            const int goff = ((c ^ (r & 7)) * 8);
            short8 af[4], bf[4];
#pragma unroll
            for (int i = 0; i < 4; ++i) {
                af[i] = *(const short8*)(ldsA + (wm0 + i * 16 + r) * 64 + goff);
                bf[i] = *(const short8*)(ldsB + (wn0 + i * 16 + r) * 64 + goff);
            }
#pragma unroll
            for (int i = 0; i < 4; ++i)
#pragma unroll
                for (int j = 0; j < 4; ++j)
                    acc[i][j] = __builtin_amdgcn_mfma_f32_16x16x32_bf16(
                        af[i], bf[j], acc[i][j], 0, 0, 0);
        }
        __syncthreads();
    }

#pragma unroll
    for (int i = 0; i < 4; ++i) {
        const int mrow = bm0 + wm0 + i * 16 + q * 4;
#pragma unroll
        for (int j = 0; j < 4; ++j) {
            const int ncol = bn0 + wn0 + j * 16 + r;
#pragma unroll
            for (int rg = 0; rg < 4; ++rg)
                C[(long)(mrow + rg) * N512 + ncol] = acc[i][j][rg];
        }
    }
}

extern "C" void kernel_launch(void* const* d_in, const int* in_sizes, int n_in,
                              void* d_out, int out_size, void* d_ws, size_t ws_size,
                              hipStream_t stream) {
    const float* X = (const float*)d_in[0];
    float* out = (float*)d_out;

    const long plane = (long)N512 * N512;          // 262144
    const int slices = in_sizes[0] / (int)plane;   // 96

    short* Mb = (short*)d_ws;                      // 512 KB
    short* Tt = Mb + plane;                        // chunk * plane bf16

    long avail = (long)ws_size - plane * 2;        // bytes after M
    int chunk = (int)(avail / (plane * 2));        // bf16 plane per slice
    if (chunk > slices) chunk = slices;
    if (chunk < 1) chunk = 1;

    build_idct_matrix_bf16<<<dim3((int)(plane / 256)), dim3(256), 0, stream>>>(Mb);

    for (int s0 = 0; s0 < slices; s0 += chunk) {
        int c = (s0 + chunk <= slices) ? chunk : (slices - s0);
        // stage 1 (reads fp32 X directly): Tt[z][n][h] = sum_k M[n,k]*X[z][h,k]
        gemm_s1<<<dim3(4, 4, c), dim3(256), 0, stream>>>(
            Mb, X + (long)s0 * plane, Tt);
        // stage 2: Out[z][m][n] = sum_h M[m,h]*Tt[z][n,h]
        gemm_s2<<<dim3(4, 4, c), dim3(256), 0, stream>>>(
            Mb, Tt, out + (long)s0 * plane);
    }
}

// Round 4
// 237.621 us; speedup vs baseline: 1.0675x; 1.0675x over previous
//
#include <hip/hip_runtime.h>
#include <math.h>
#include <stdint.h>

#define N512 512

typedef __attribute__((ext_vector_type(8))) short short8;
typedef __attribute__((ext_vector_type(4))) float floatx4;

__device__ __forceinline__ short f2bf(float f) {
    uint32_t u = __float_as_uint(f);
    uint32_t r = u + 0x7fffu + ((u >> 16) & 1u);
    return (short)(r >> 16);
}

// cheap round-half-up (2 VALU): fine vs 0.109 threshold
__device__ __forceinline__ short f2bf_fast(float f) {
    return (short)((__float_as_uint(f) + 0x8000u) >> 16);
}

__device__ __forceinline__ void gload_lds16(const void* g, void* l) {
    __builtin_amdgcn_global_load_lds(
        (const __attribute__((address_space(1))) void*)g,
        (__attribute__((address_space(3))) void*)l,
        16, 0, 0);
}

// M[n,k] = s_k * cos(pi * k * (2n+1) / (2N)), bf16 (RNE-ish)
__global__ __launch_bounds__(256) void build_idct_matrix_bf16(short* __restrict__ M) {
    int idx = blockIdx.x * 256 + threadIdx.x;
    int n = idx >> 9;
    int k = idx & 511;
    int j = (k * (2 * n + 1)) & (4 * N512 - 1);
    float theta = (float)j * (3.14159265358979323846f / (2.0f * (float)N512));
    float s = (k == 0) ? 0.044194173824159216f : 0.0625f;
    M[idx] = f2bf(s * cosf(theta));
}

// ---------------------------------------------------------------------------
// Stage 1 (fused cvt): Tt[z][n][h] = sum_k M[n,k] * X[z][h,k]
// A = M bf16 via global_load_lds(16B, XOR swizzle). B = X fp32 loaded with
// fully-coalesced float4 (16 lanes cover one 256B row segment), converted
// in-register to bf16, ds_write_b64 into the same swizzled layout.
// 128x128 tile, BK=64, 4 waves, each 4x4 of 16x16x32 bf16 MFMA.
// ---------------------------------------------------------------------------
__global__ __launch_bounds__(256) void gemm_s1(const short* __restrict__ A,
                                               const float* __restrict__ Xg,
                                               short* __restrict__ Tg) {
    __shared__ short lds[2 * 8192];   // A tile 128x64 (16KB) | B tile (16KB)
    short* ldsA = lds;
    short* ldsB = lds + 8192;

    const int t = threadIdx.x;
    const int w = t >> 6;          // wave 0..3
    const int l = t & 63;
    const int q = (t >> 4) & 3;    // quad in wave
    const int r = t & 15;

    const int bm0 = blockIdx.y * 128;   // A rows (n)
    const int bn0 = blockIdx.x * 128;   // B rows (h)
    const int wm0 = (w >> 1) * 64;
    const int wn0 = (w & 1) * 64;

    const float* Xs = Xg + ((long)blockIdx.z << 18);
    short* Tt = Tg + ((long)blockIdx.z << 18);

    // A staging: instr i of wave w covers tile rows (w*4+i)*8 .. +7
    const int rsub = l >> 3;                 // row within 8-row chunk
    const int glog = (l & 7) ^ rsub;         // swizzled 16B-group to fetch

    // B staging: pass p: row rt = p*16 + (t>>4); float4 at col (t&15)*4
    const int brow = t >> 4;                 // 0..15 (row within pass)
    const int col4 = t & 15;                 // float4 index in row
    const int bg   = col4 >> 1;              // 8-float group 0..7
    const int bh   = col4 & 1;               // half of group

    floatx4 acc[4][4] = {};

    for (int kt = 0; kt < 8; ++kt) {
        const int k0 = kt * 64;
        // A -> LDS via DMA
#pragma unroll
        for (int i = 0; i < 4; ++i) {
            const int chunk = w * 4 + i;
            const int rt = chunk * 8 + rsub;
            gload_lds16(A + (((long)(bm0 + rt)) << 9) + k0 + glog * 8,
                        ldsA + chunk * 512);
        }
        // B: 8 passes, coalesced float4 loads (independent -> hoisted)
        {
            float4 v[8];
#pragma unroll
            for (int p = 0; p < 8; ++p) {
                const int rt = p * 16 + brow;
                v[p] = *(const float4*)(Xs + (((long)(bn0 + rt)) << 9) + k0 + col4 * 4);
            }
#pragma unroll
            for (int p = 0; p < 8; ++p) {
                const int rt = p * 16 + brow;
                const int bchunk = rt >> 3;
                const int brs = rt & 7;
                short4 o;
                o.x = f2bf_fast(v[p].x);
                o.y = f2bf_fast(v[p].y);
                o.z = f2bf_fast(v[p].z);
                o.w = f2bf_fast(v[p].w);
                *(short4*)(ldsB + bchunk * 512 + brs * 64 + ((bg ^ brs) * 8) + bh * 4) = o;
            }
        }
        __syncthreads();
#pragma unroll
        for (int kk = 0; kk < 2; ++kk) {
            const int c = kk * 4 + q;
            const int goff = ((c ^ (r & 7)) * 8);
            short8 af[4], bf[4];
#pragma unroll
            for (int i = 0; i < 4; ++i) {
                af[i] = *(const short8*)(ldsA + (wm0 + i * 16 + r) * 64 + goff);
                bf[i] = *(const short8*)(ldsB + (wn0 + i * 16 + r) * 64 + goff);
            }
#pragma unroll
            for (int i = 0; i < 4; ++i)
#pragma unroll
                for (int j = 0; j < 4; ++j)
                    acc[i][j] = __builtin_amdgcn_mfma_f32_16x16x32_bf16(
                        af[i], bf[j], acc[i][j], 0, 0, 0);
        }
        __syncthreads();
    }

    // epilogue: D row = quad*4+reg, col = lane&15 (bf16 out)
#pragma unroll
    for (int i = 0; i < 4; ++i) {
        const int mrow = bm0 + wm0 + i * 16 + q * 4;
#pragma unroll
        for (int j = 0; j < 4; ++j) {
            const int ncol = bn0 + wn0 + j * 16 + r;
#pragma unroll
            for (int rg = 0; rg < 4; ++rg)
                Tt[(long)(mrow + rg) * N512 + ncol] = f2bf(acc[i][j][rg]);
        }
    }
}

// ---------------------------------------------------------------------------
// Stage 2: Out[z][m][n] = sum_h M[m,h] * Tt[z][n,h]  (both bf16, fp32 out)
// ---------------------------------------------------------------------------
__global__ __launch_bounds__(256) void gemm_s2(const short* __restrict__ A,
                                               const short* __restrict__ Bg,
                                               float* __restrict__ Cg) {
    __shared__ short lds[2 * 8192];
    short* ldsA = lds;
    short* ldsB = lds + 8192;

    const int t = threadIdx.x;
    const int w = t >> 6;
    const int l = t & 63;
    const int q = (t >> 4) & 3;
    const int r = t & 15;

    const int bm0 = blockIdx.y * 128;
    const int bn0 = blockIdx.x * 128;
    const int wm0 = (w >> 1) * 64;
    const int wn0 = (w & 1) * 64;

    const short* Bs = Bg + ((long)blockIdx.z << 18);
    float* C = Cg + ((long)blockIdx.z << 18);

    const int rsub = l >> 3;
    const int glog = (l & 7) ^ rsub;

    floatx4 acc[4][4] = {};

    for (int kt = 0; kt < 8; ++kt) {
        const int k0 = kt * 64;
#pragma unroll
        for (int i = 0; i < 4; ++i) {
            const int chunk = w * 4 + i;
            const int rt = chunk * 8 + rsub;
            gload_lds16(A + (((long)(bm0 + rt)) << 9) + k0 + glog * 8,
                        ldsA + chunk * 512);
            gload_lds16(Bs + (((long)(bn0 + rt)) << 9) + k0 + glog * 8,
                        ldsB + chunk * 512);
        }
        __syncthreads();
#pragma unroll
        for (int kk = 0; kk < 2; ++kk) {
            const int c = kk * 4 + q;
            const int goff = ((c ^ (r & 7)) * 8);
            short8 af[4], bf[4];
#pragma unroll
            for (int i = 0; i < 4; ++i) {
                af[i] = *(const short8*)(ldsA + (wm0 + i * 16 + r) * 64 + goff);
                bf[i] = *(const short8*)(ldsB + (wn0 + i * 16 + r) * 64 + goff);
            }
#pragma unroll
            for (int i = 0; i < 4; ++i)
#pragma unroll
                for (int j = 0; j < 4; ++j)
                    acc[i][j] = __builtin_amdgcn_mfma_f32_16x16x32_bf16(
                        af[i], bf[j], acc[i][j], 0, 0, 0);
        }
        __syncthreads();
    }

#pragma unroll
    for (int i = 0; i < 4; ++i) {
        const int mrow = bm0 + wm0 + i * 16 + q * 4;
#pragma unroll
        for (int j = 0; j < 4; ++j) {
            const int ncol = bn0 + wn0 + j * 16 + r;
#pragma unroll
            for (int rg = 0; rg < 4; ++rg)
                C[(long)(mrow + rg) * N512 + ncol] = acc[i][j][rg];
        }
    }
}

extern "C" void kernel_launch(void* const* d_in, const int* in_sizes, int n_in,
                              void* d_out, int out_size, void* d_ws, size_t ws_size,
                              hipStream_t stream) {
    const float* X = (const float*)d_in[0];
    float* out = (float*)d_out;

    const long plane = (long)N512 * N512;          // 262144
    const int slices = in_sizes[0] / (int)plane;   // 96

    short* Mb = (short*)d_ws;                      // 512 KB
    short* Tt = Mb + plane;                        // chunk * plane bf16

    long avail = (long)ws_size - plane * 2;        // bytes after M
    int chunk = (int)(avail / (plane * 2));        // bf16 plane per slice
    if (chunk > slices) chunk = slices;
    if (chunk < 1) chunk = 1;

    build_idct_matrix_bf16<<<dim3((int)(plane / 256)), dim3(256), 0, stream>>>(Mb);

    for (int s0 = 0; s0 < slices; s0 += chunk) {
        int c = (s0 + chunk <= slices) ? chunk : (slices - s0);
        // stage 1 (reads fp32 X directly): Tt[z][n][h] = sum_k M[n,k]*X[z][h,k]
        gemm_s1<<<dim3(4, 4, c), dim3(256), 0, stream>>>(
            Mb, X + (long)s0 * plane, Tt);
        // stage 2: Out[z][m][n] = sum_h M[m,h]*Tt[z][n,h]
        gemm_s2<<<dim3(4, 4, c), dim3(256), 0, stream>>>(
            Mb, Tt, out + (long)s0 * plane);
    }
}